// Round 5
// baseline (276.448 us; speedup 1.0000x reference)
//
#include <hip/hip_runtime.h>
#include <hip/hip_bf16.h>

typedef __attribute__((ext_vector_type(8))) short bf16x8;
typedef __attribute__((ext_vector_type(4))) float f32x4;
typedef unsigned short u16;
typedef unsigned int u32;

// ---------- helpers ----------

__device__ __forceinline__ u16 f2bf(float f) {
  __hip_bfloat16 h = __float2bfloat16(f);
  return *reinterpret_cast<u16*>(&h);
}

__device__ __forceinline__ void async16(const void* g, void* l) {
  __builtin_amdgcn_global_load_lds((const __attribute__((address_space(1))) u32*)g,
                                   (__attribute__((address_space(3))) u32*)l, 16, 0, 0);
}

// ---------- cast f32 -> bf16 (vectorized) ----------

__global__ void cast_bf16(const float4* __restrict__ src, ushort4* __restrict__ dst, int n4) {
  int stride = gridDim.x * blockDim.x;
  for (int i = blockIdx.x * blockDim.x + threadIdx.x; i < n4; i += stride) {
    float4 v = src[i];
    ushort4 o;
    o.x = f2bf(v.x); o.y = f2bf(v.y); o.z = f2bf(v.z); o.w = f2bf(v.w);
    dst[i] = o;
  }
}

__global__ void cast_w4(const float4* __restrict__ w0, const float4* __restrict__ w1,
                        const float4* __restrict__ w2, const float4* __restrict__ w3,
                        ushort4* __restrict__ o0, ushort4* __restrict__ o1,
                        ushort4* __restrict__ o2, ushort4* __restrict__ o3, int n4) {
  const float4* src = (blockIdx.y == 0) ? w0 : (blockIdx.y == 1) ? w1 : (blockIdx.y == 2) ? w2 : w3;
  ushort4* dst = (blockIdx.y == 0) ? o0 : (blockIdx.y == 1) ? o1 : (blockIdx.y == 2) ? o2 : o3;
  int stride = gridDim.x * blockDim.x;
  for (int i = blockIdx.x * blockDim.x + threadIdx.x; i < n4; i += stride) {
    float4 v = src[i];
    ushort4 o;
    o.x = f2bf(v.x); o.y = f2bf(v.y); o.z = f2bf(v.z); o.w = f2bf(v.w);
    dst[i] = o;
  }
}

// ---------- RoPE cos/sin table: [2048 pos][32 freq] ----------

__global__ void rope_table(float* __restrict__ tcos, float* __restrict__ tsin) {
  int idx = blockIdx.x * blockDim.x + threadIdx.x;
  if (idx >= 2048 * 32) return;
  int c = idx >> 5, j = idx & 31;
  float inv = powf(10000.f, -(float)j * (1.f / 32.f));
  float ang = (float)c * inv;
  tcos[idx] = cosf(ang);
  tsin[idx] = sinf(ang);
}

// ---------- QKV projection GEMM (y = x @ W^T), RoPE fused for Q/K ----------
// z=0: Q (+rope) -> [B,H,C,D], z=1: K (+rope) -> [B,H,C,D], z=2: V -> [B,H,D,C] (transposed)

__launch_bounds__(256)
__global__ void qkv_gemm(const u16* __restrict__ xb, const u16* __restrict__ Wqb,
                         const u16* __restrict__ Wkb, const u16* __restrict__ Wvb,
                         const float* __restrict__ tcos, const float* __restrict__ tsin,
                         u16* __restrict__ Qr, u16* __restrict__ Kr, u16* __restrict__ Vt) {
  const int z = blockIdx.z;
  const u16* W = (z == 0) ? Wqb : (z == 1) ? Wkb : Wvb;
  u16* dst = (z == 0) ? Qr : (z == 1) ? Kr : Vt;
  const int m0 = blockIdx.y * 128, n0 = blockIdx.x * 128;
  const int tid = threadIdx.x, w = tid >> 6, lane = tid & 63, g = lane >> 4, cl = lane & 15;
  const int wr = w >> 1, wc = w & 1;
  __shared__ u16 As[128][32], Bs[128][32];
  f32x4 acc[4][4] = {};
  for (int k0 = 0; k0 < 1024; k0 += 32) {
#pragma unroll
    for (int ch = 0; ch < 2; ++ch) {
      int t = tid + ch * 256;
      int row = t >> 2, col = (t & 3) * 8;
      async16(&xb[(size_t)(m0 + row) * 1024 + k0 + col], &As[row][col]);
      async16(&W[(size_t)(n0 + row) * 1024 + k0 + col], &Bs[row][col]);
    }
    __syncthreads();
    bf16x8 af[4], bfr[4];
#pragma unroll
    for (int i = 0; i < 4; ++i) af[i] = *(const bf16x8*)&As[wr * 64 + i * 16 + cl][g * 8];
#pragma unroll
    for (int j = 0; j < 4; ++j) bfr[j] = *(const bf16x8*)&Bs[wc * 64 + j * 16 + cl][g * 8];
#pragma unroll
    for (int i = 0; i < 4; ++i)
#pragma unroll
      for (int j = 0; j < 4; ++j)
        acc[i][j] = __builtin_amdgcn_mfma_f32_16x16x32_bf16(af[i], bfr[j], acc[i][j], 0, 0, 0);
    __syncthreads();
  }
  if (z < 2) {
#pragma unroll
    for (int i = 0; i < 4; ++i) {
      int mbase = m0 + wr * 64 + i * 16 + g * 4;
#pragma unroll
      for (int r = 0; r < 4; ++r) {
        int mm = mbase + r;
        int b = mm >> 11, pos = mm & 2047;
#pragma unroll
        for (int j = 0; j < 2; ++j) {
          int n = n0 + wc * 64 + j * 16 + cl;
          int h = n >> 6, dlo = n & 63;
          float a = acc[i][j][r], b2 = acc[i][j + 2][r];
          float cv = tcos[pos * 32 + dlo], sv = tsin[pos * 32 + dlo];
          float o1 = a * cv - b2 * sv;
          float o2 = b2 * cv + a * sv;
          size_t base = ((size_t)(b * 16 + h) * 2048 + pos) * 64;
          dst[base + dlo] = f2bf(o1);
          dst[base + dlo + 32] = f2bf(o2);
        }
      }
    }
  } else {
#pragma unroll
    for (int i = 0; i < 4; ++i) {
      int mbase = m0 + wr * 64 + i * 16 + g * 4;
      int b = mbase >> 11, pos = mbase & 2047;
#pragma unroll
      for (int j = 0; j < 4; ++j) {
        int n = n0 + wc * 64 + j * 16 + cl;
        int h = n >> 6, d = n & 63;
        ushort4 v4;
        v4.x = f2bf(acc[i][j][0]);
        v4.y = f2bf(acc[i][j][1]);
        v4.z = f2bf(acc[i][j][2]);
        v4.w = f2bf(acc[i][j][3]);
        *(ushort4*)&dst[((size_t)(b * 16 + h) * 64 + d) * 2048 + pos] = v4;
      }
    }
  }
}

// ---------- flash attention (causal), 2 waves/block, causal-paired q-tiles ----------
// Pair p: wave0 -> qt=63-p, wave1 -> qt=p. work(qt)=qt/2+1 K-tiles; pair sum = 33 always.
// Q/K: [B*H, 2048, 64] bf16.  Vt: [B*H, 64, 2048] bf16.  hid: [B, C, H*D] bf16.

__launch_bounds__(128)
__global__ void attn_kernel(const u16* __restrict__ Qr, const u16* __restrict__ Kr,
                            const u16* __restrict__ Vt, u16* __restrict__ hid) {
  const int bid = blockIdx.x;
  const int xcd = bid & 7, jj = bid >> 3;      // 1024 blocks: 8 xcd x 4 bh x 32 pairs
  const int bh = xcd * 4 + (jj >> 5);
  const int p = jj & 31;
  const int wid = threadIdx.x >> 6;
  const int qt = wid ? p : 63 - p;
  const int lane = threadIdx.x & 63, g = lane >> 4, cl = lane & 15;
  const int b = bh >> 4, h = bh & 15;
  const int qbase = qt * 32;
  const u16* Qp = Qr + (size_t)bh * 2048 * 64;
  const u16* Kp = Kr + (size_t)bh * 2048 * 64;
  const u16* Vp = Vt + (size_t)bh * 2048 * 64;
  __shared__ u16 P_all[2][32 * 64];  // per-wave private, XOR-swizzled
  u16* P_lds = P_all[wid];

  // Q fragments: aq[qg*2+ks]
  bf16x8 aq[4];
#pragma unroll
  for (int qg = 0; qg < 2; ++qg)
#pragma unroll
    for (int ks = 0; ks < 2; ++ks)
      aq[qg * 2 + ks] = *(const bf16x8*)&Qp[(size_t)(qbase + qg * 16 + cl) * 64 + ks * 32 + g * 8];

  f32x4 ot[8] = {};             // O^T frags: ot[qg*4+j], rows=d (g*4+r), col=q(cl)
  float mrow[8], lrow[8];       // [qg*4+r]
#pragma unroll
  for (int r = 0; r < 8; ++r) { mrow[r] = -__builtin_inff(); lrow[r] = 0.f; }

  const int ktmax = qt >> 1;

  auto loadK = [&](bf16x8* dst, int kt_) {
#pragma unroll
    for (int n = 0; n < 4; ++n)
#pragma unroll
      for (int ks = 0; ks < 2; ++ks)
        dst[n * 2 + ks] = *(const bf16x8*)&Kp[(size_t)(kt_ * 64 + n * 16 + cl) * 64 + ks * 32 + g * 8];
  };
  auto loadV = [&](bf16x8* dst, int kt_) {
#pragma unroll
    for (int ks = 0; ks < 2; ++ks)
#pragma unroll
      for (int j = 0; j < 4; ++j)
        dst[ks * 4 + j] = *(const bf16x8*)&Vp[(size_t)(j * 16 + cl) * 2048 + kt_ * 64 + ks * 32 + g * 8];
  };

  auto tile = [&](const bf16x8* kf, const bf16x8* bv, int kt_, bool diag) {
    f32x4 s[8] = {};  // s[qg*4+n]: rows=q(g*4+r), col=k(n*16+cl)
#pragma unroll
    for (int qg = 0; qg < 2; ++qg)
#pragma unroll
      for (int n = 0; n < 4; ++n)
#pragma unroll
        for (int ks = 0; ks < 2; ++ks)
          s[qg * 4 + n] = __builtin_amdgcn_mfma_f32_16x16x32_bf16(aq[qg * 2 + ks], kf[n * 2 + ks],
                                                                  s[qg * 4 + n], 0, 0, 0);
    // scale + mask
    if (diag) {
#pragma unroll
      for (int qg = 0; qg < 2; ++qg)
#pragma unroll
        for (int n = 0; n < 4; ++n)
#pragma unroll
          for (int r = 0; r < 4; ++r) {
            int q = qbase + qg * 16 + g * 4 + r, k = kt_ * 64 + n * 16 + cl;
            s[qg * 4 + n][r] = (k <= q) ? s[qg * 4 + n][r] * 0.125f : -__builtin_inff();
          }
    } else {
#pragma unroll
      for (int i = 0; i < 8; ++i)
#pragma unroll
        for (int r = 0; r < 4; ++r) s[i][r] *= 0.125f;
    }
    bf16x8 ap[4];
#pragma unroll
    for (int qg = 0; qg < 2; ++qg) {
      float pmax[4], ef[4];
#pragma unroll
      for (int r = 0; r < 4; ++r) {
        float v = fmaxf(fmaxf(s[qg * 4 + 0][r], s[qg * 4 + 1][r]),
                        fmaxf(s[qg * 4 + 2][r], s[qg * 4 + 3][r]));
#pragma unroll
        for (int off = 1; off < 16; off <<= 1) v = fmaxf(v, __shfl_xor(v, off));
        pmax[r] = v;
      }
#pragma unroll
      for (int r = 0; r < 4; ++r) {
        float mnew = fmaxf(mrow[qg * 4 + r], pmax[r]);
        ef[r] = __expf(mrow[qg * 4 + r] - mnew);
        mrow[qg * 4 + r] = mnew;
      }
      float rs[4] = {0.f, 0.f, 0.f, 0.f};
#pragma unroll
      for (int n = 0; n < 4; ++n)
#pragma unroll
        for (int r = 0; r < 4; ++r) {
          float p2 = __expf(s[qg * 4 + n][r] - mrow[qg * 4 + r]);
          s[qg * 4 + n][r] = p2;
          rs[r] += p2;
          int row = qg * 16 + g * 4 + r;
          P_lds[(row * 64 + n * 16 + cl) ^ ((row & 7) << 3)] = f2bf(p2);
        }
#pragma unroll
      for (int r = 0; r < 4; ++r) {
        float v = rs[r];
#pragma unroll
        for (int off = 1; off < 16; off <<= 1) v += __shfl_xor(v, off);
        lrow[qg * 4 + r] = lrow[qg * 4 + r] * ef[r] + v;
      }
      // transpose ef to per-lane (for O^T col q=cl)
      int src = ((cl >> 2) << 4) | cl;
      float t0 = __shfl(ef[0], src), t1 = __shfl(ef[1], src);
      float t2 = __shfl(ef[2], src), t3 = __shfl(ef[3], src);
      float eft = (cl & 2) ? ((cl & 1) ? t3 : t2) : ((cl & 1) ? t1 : t0);
#pragma unroll
      for (int j = 0; j < 4; ++j)
#pragma unroll
        for (int r = 0; r < 4; ++r) ot[qg * 4 + j][r] *= eft;
      // read P fragments (B-role for swapped PV)
#pragma unroll
      for (int ks = 0; ks < 2; ++ks) {
        int rowr = qg * 16 + cl;
        ap[qg * 2 + ks] = *(const bf16x8*)&P_lds[(rowr * 64 + ks * 32 + g * 8) ^ ((rowr & 7) << 3)];
      }
    }
    // PV swapped: O^T = V^T * P^T
#pragma unroll
    for (int qg = 0; qg < 2; ++qg)
#pragma unroll
      for (int ks = 0; ks < 2; ++ks)
#pragma unroll
        for (int j = 0; j < 4; ++j)
          ot[qg * 4 + j] = __builtin_amdgcn_mfma_f32_16x16x32_bf16(bv[ks * 4 + j], ap[qg * 2 + ks],
                                                                   ot[qg * 4 + j], 0, 0, 0);
  };

  bf16x8 kA[8], kB[8], bv[8];
  loadK(kA, 0);
  for (int kt = 0; kt <= ktmax; kt += 2) {
    loadV(bv, kt);
    if (kt + 1 <= ktmax) loadK(kB, kt + 1);
    tile(kA, bv, kt, kt == ktmax);
    if (kt + 1 <= ktmax) {
      loadV(bv, kt + 1);
      if (kt + 2 <= ktmax) loadK(kA, kt + 2);
      tile(kB, bv, kt + 1, kt + 1 == ktmax);
    }
  }

  // epilogue: O^T rows d = j*16+g*4+r, col q = qbase+qg*16+cl; transpose l to per-lane
#pragma unroll
  for (int qg = 0; qg < 2; ++qg) {
    int src = ((cl >> 2) << 4) | cl;
    float t0 = __shfl(lrow[qg * 4 + 0], src), t1 = __shfl(lrow[qg * 4 + 1], src);
    float t2 = __shfl(lrow[qg * 4 + 2], src), t3 = __shfl(lrow[qg * 4 + 3], src);
    float lt = (cl & 2) ? ((cl & 1) ? t3 : t2) : ((cl & 1) ? t1 : t0);
    float inv = 1.f / lt;
    int q = qbase + qg * 16 + cl;
#pragma unroll
    for (int j = 0; j < 4; ++j) {
      ushort4 v4;
      v4.x = f2bf(ot[qg * 4 + j][0] * inv);
      v4.y = f2bf(ot[qg * 4 + j][1] * inv);
      v4.z = f2bf(ot[qg * 4 + j][2] * inv);
      v4.w = f2bf(ot[qg * 4 + j][3] * inv);
      *(ushort4*)&hid[((size_t)(b * 2048) + q) * 1024 + h * 64 + j * 16 + g * 4] = v4;
    }
  }
}

// ---------- output projection: out = hid @ Wo^T (f32 out) ----------

__launch_bounds__(256)
__global__ void out_gemm(const u16* __restrict__ hb, const u16* __restrict__ Wob,
                         float* __restrict__ out) {
  const int m0 = blockIdx.y * 128, n0 = blockIdx.x * 128;
  const int tid = threadIdx.x, w = tid >> 6, lane = tid & 63, g = lane >> 4, cl = lane & 15;
  const int wr = w >> 1, wc = w & 1;
  __shared__ u16 As[128][32], Bs[128][32];
  f32x4 acc[4][4] = {};
  for (int k0 = 0; k0 < 1024; k0 += 32) {
#pragma unroll
    for (int ch = 0; ch < 2; ++ch) {
      int t = tid + ch * 256;
      int row = t >> 2, col = (t & 3) * 8;
      async16(&hb[(size_t)(m0 + row) * 1024 + k0 + col], &As[row][col]);
      async16(&Wob[(size_t)(n0 + row) * 1024 + k0 + col], &Bs[row][col]);
    }
    __syncthreads();
    bf16x8 af[4], bfr[4];
#pragma unroll
    for (int i = 0; i < 4; ++i) af[i] = *(const bf16x8*)&As[wr * 64 + i * 16 + cl][g * 8];
#pragma unroll
    for (int j = 0; j < 4; ++j) bfr[j] = *(const bf16x8*)&Bs[wc * 64 + j * 16 + cl][g * 8];
#pragma unroll
    for (int i = 0; i < 4; ++i)
#pragma unroll
      for (int j = 0; j < 4; ++j)
        acc[i][j] = __builtin_amdgcn_mfma_f32_16x16x32_bf16(af[i], bfr[j], acc[i][j], 0, 0, 0);
    __syncthreads();
  }
#pragma unroll
  for (int i = 0; i < 4; ++i)
#pragma unroll
    for (int r = 0; r < 4; ++r) {
      int m = m0 + wr * 64 + i * 16 + g * 4 + r;
#pragma unroll
      for (int j = 0; j < 4; ++j)
        out[(size_t)m * 1024 + n0 + wc * 64 + j * 16 + cl] = acc[i][j][r];
    }
}

// ---------- launch ----------

extern "C" void kernel_launch(void* const* d_in, const int* in_sizes, int n_in,
                              void* d_out, int out_size, void* d_ws, size_t ws_size,
                              hipStream_t stream) {
  const float* x = (const float*)d_in[0];
  const float* Wq = (const float*)d_in[1];
  const float* Wk = (const float*)d_in[2];
  const float* Wv = (const float*)d_in[3];
  const float* Wo = (const float*)d_in[4];
  float* out = (float*)d_out;

  char* ws = (char*)d_ws;
  size_t off = 0;
  auto alloc = [&](size_t bytes) {
    void* p = ws + off;
    off += (bytes + 255) & ~(size_t)255;
    return p;
  };
  u16* xb = (u16*)alloc(4096ull * 1024 * 2);
  u16* Wqb = (u16*)alloc(1024ull * 1024 * 2);
  u16* Wkb = (u16*)alloc(1024ull * 1024 * 2);
  u16* Wvb = (u16*)alloc(1024ull * 1024 * 2);
  u16* Wob = (u16*)alloc(1024ull * 1024 * 2);
  u16* Qr = (u16*)alloc(4096ull * 1024 * 2);
  u16* Kr = (u16*)alloc(4096ull * 1024 * 2);
  u16* Vt = (u16*)alloc(4096ull * 1024 * 2);
  u16* hid = (u16*)alloc(4096ull * 1024 * 2);
  float* tcos = (float*)alloc(2048ull * 32 * 4);
  float* tsin = (float*)alloc(2048ull * 32 * 4);

  cast_bf16<<<1024, 256, 0, stream>>>((const float4*)x, (ushort4*)xb, 4096 * 1024 / 4);
  cast_w4<<<dim3(256, 4), 256, 0, stream>>>((const float4*)Wq, (const float4*)Wk,
                                            (const float4*)Wv, (const float4*)Wo,
                                            (ushort4*)Wqb, (ushort4*)Wkb,
                                            (ushort4*)Wvb, (ushort4*)Wob, 1024 * 1024 / 4);
  rope_table<<<256, 256, 0, stream>>>(tcos, tsin);

  qkv_gemm<<<dim3(8, 32, 3), 256, 0, stream>>>(xb, Wqb, Wkb, Wvb, tcos, tsin, Qr, Kr, Vt);
  attn_kernel<<<1024, 128, 0, stream>>>(Qr, Kr, Vt, hid);
  out_gemm<<<dim3(8, 32), 256, 0, stream>>>(hid, Wob, out);
}

// Round 6
// 272.486 us; speedup vs baseline: 1.0145x; 1.0145x over previous
//
#include <hip/hip_runtime.h>
#include <hip/hip_bf16.h>

typedef __attribute__((ext_vector_type(8))) short bf16x8;
typedef __attribute__((ext_vector_type(4))) float f32x4;
typedef unsigned short u16;
typedef unsigned int u32;

#define SM_SCALE 0.18033688f  // 0.125 * log2(e): softmax in exp2 domain

// ---------- helpers ----------

__device__ __forceinline__ u16 f2bf(float f) {
  __hip_bfloat16 h = __float2bfloat16(f);
  return *reinterpret_cast<u16*>(&h);
}

__device__ __forceinline__ void async16(const void* g, void* l) {
  __builtin_amdgcn_global_load_lds((const __attribute__((address_space(1))) u32*)g,
                                   (__attribute__((address_space(3))) u32*)l, 16, 0, 0);
}

// ---------- cast f32 -> bf16 (vectorized) ----------

__global__ void cast_bf16(const float4* __restrict__ src, ushort4* __restrict__ dst, int n4) {
  int stride = gridDim.x * blockDim.x;
  for (int i = blockIdx.x * blockDim.x + threadIdx.x; i < n4; i += stride) {
    float4 v = src[i];
    ushort4 o;
    o.x = f2bf(v.x); o.y = f2bf(v.y); o.z = f2bf(v.z); o.w = f2bf(v.w);
    dst[i] = o;
  }
}

__global__ void cast_w4(const float4* __restrict__ w0, const float4* __restrict__ w1,
                        const float4* __restrict__ w2, const float4* __restrict__ w3,
                        ushort4* __restrict__ o0, ushort4* __restrict__ o1,
                        ushort4* __restrict__ o2, ushort4* __restrict__ o3, int n4) {
  const float4* src = (blockIdx.y == 0) ? w0 : (blockIdx.y == 1) ? w1 : (blockIdx.y == 2) ? w2 : w3;
  ushort4* dst = (blockIdx.y == 0) ? o0 : (blockIdx.y == 1) ? o1 : (blockIdx.y == 2) ? o2 : o3;
  int stride = gridDim.x * blockDim.x;
  for (int i = blockIdx.x * blockDim.x + threadIdx.x; i < n4; i += stride) {
    float4 v = src[i];
    ushort4 o;
    o.x = f2bf(v.x); o.y = f2bf(v.y); o.z = f2bf(v.z); o.w = f2bf(v.w);
    dst[i] = o;
  }
}

// ---------- RoPE cos/sin table: [2048 pos][32 freq] ----------

__global__ void rope_table(float* __restrict__ tcos, float* __restrict__ tsin) {
  int idx = blockIdx.x * blockDim.x + threadIdx.x;
  if (idx >= 2048 * 32) return;
  int c = idx >> 5, j = idx & 31;
  float inv = powf(10000.f, -(float)j * (1.f / 32.f));
  float ang = (float)c * inv;
  tcos[idx] = cosf(ang);
  tsin[idx] = sinf(ang);
}

// ---------- QKV projection GEMM (y = x @ W^T), RoPE fused for Q/K ----------
// z=0: Q (+rope) -> [B,H,C,D], z=1: K (+rope) -> [B,H,C,D], z=2: V -> [B,H,D,C] (transposed)

__launch_bounds__(256)
__global__ void qkv_gemm(const u16* __restrict__ xb, const u16* __restrict__ Wqb,
                         const u16* __restrict__ Wkb, const u16* __restrict__ Wvb,
                         const float* __restrict__ tcos, const float* __restrict__ tsin,
                         u16* __restrict__ Qr, u16* __restrict__ Kr, u16* __restrict__ Vt) {
  const int z = blockIdx.z;
  const u16* W = (z == 0) ? Wqb : (z == 1) ? Wkb : Wvb;
  u16* dst = (z == 0) ? Qr : (z == 1) ? Kr : Vt;
  const int m0 = blockIdx.y * 128, n0 = blockIdx.x * 128;
  const int tid = threadIdx.x, w = tid >> 6, lane = tid & 63, g = lane >> 4, cl = lane & 15;
  const int wr = w >> 1, wc = w & 1;
  __shared__ u16 As[128][32], Bs[128][32];
  f32x4 acc[4][4] = {};
  for (int k0 = 0; k0 < 1024; k0 += 32) {
#pragma unroll
    for (int ch = 0; ch < 2; ++ch) {
      int t = tid + ch * 256;
      int row = t >> 2, col = (t & 3) * 8;
      async16(&xb[(size_t)(m0 + row) * 1024 + k0 + col], &As[row][col]);
      async16(&W[(size_t)(n0 + row) * 1024 + k0 + col], &Bs[row][col]);
    }
    __syncthreads();
    bf16x8 af[4], bfr[4];
#pragma unroll
    for (int i = 0; i < 4; ++i) af[i] = *(const bf16x8*)&As[wr * 64 + i * 16 + cl][g * 8];
#pragma unroll
    for (int j = 0; j < 4; ++j) bfr[j] = *(const bf16x8*)&Bs[wc * 64 + j * 16 + cl][g * 8];
#pragma unroll
    for (int i = 0; i < 4; ++i)
#pragma unroll
      for (int j = 0; j < 4; ++j)
        acc[i][j] = __builtin_amdgcn_mfma_f32_16x16x32_bf16(af[i], bfr[j], acc[i][j], 0, 0, 0);
    __syncthreads();
  }
  if (z < 2) {
#pragma unroll
    for (int i = 0; i < 4; ++i) {
      int mbase = m0 + wr * 64 + i * 16 + g * 4;
#pragma unroll
      for (int r = 0; r < 4; ++r) {
        int mm = mbase + r;
        int b = mm >> 11, pos = mm & 2047;
#pragma unroll
        for (int j = 0; j < 2; ++j) {
          int n = n0 + wc * 64 + j * 16 + cl;
          int h = n >> 6, dlo = n & 63;
          float a = acc[i][j][r], b2 = acc[i][j + 2][r];
          float cv = tcos[pos * 32 + dlo], sv = tsin[pos * 32 + dlo];
          float o1 = a * cv - b2 * sv;
          float o2 = b2 * cv + a * sv;
          size_t base = ((size_t)(b * 16 + h) * 2048 + pos) * 64;
          dst[base + dlo] = f2bf(o1);
          dst[base + dlo + 32] = f2bf(o2);
        }
      }
    }
  } else {
#pragma unroll
    for (int i = 0; i < 4; ++i) {
      int mbase = m0 + wr * 64 + i * 16 + g * 4;
      int b = mbase >> 11, pos = mbase & 2047;
#pragma unroll
      for (int j = 0; j < 4; ++j) {
        int n = n0 + wc * 64 + j * 16 + cl;
        int h = n >> 6, d = n & 63;
        ushort4 v4;
        v4.x = f2bf(acc[i][j][0]);
        v4.y = f2bf(acc[i][j][1]);
        v4.z = f2bf(acc[i][j][2]);
        v4.w = f2bf(acc[i][j][3]);
        *(ushort4*)&dst[((size_t)(b * 16 + h) * 64 + d) * 2048 + pos] = v4;
      }
    }
  }
}

// ---------- flash attention (causal), 2 waves/block SPLIT-K over kt ----------
// Block = one 32-row q-tile. wave0: even kt, wave1: odd kt; merge via LDS at end.
// Q/K: [B*H, 2048, 64] bf16.  Vt: [B*H, 64, 2048] bf16.  hid: [B, C, H*D] bf16.

__launch_bounds__(128)
__global__ void attn_kernel(const u16* __restrict__ Qr, const u16* __restrict__ Kr,
                            const u16* __restrict__ Vt, u16* __restrict__ hid) {
  const int bid = blockIdx.x;
  const int xcd = bid & 7, jj = bid >> 3;      // 2048 blocks: 8 xcd x 4 bh x 64 qt
  const int bh = xcd * 4 + (jj >> 6);
  const int qt = 63 - (jj & 63);               // heavy q-tiles first
  const int wid = threadIdx.x >> 6;
  const int lane = threadIdx.x & 63, g = lane >> 4, cl = lane & 15;
  const int b = bh >> 4, h = bh & 15;
  const int qbase = qt * 32;
  const u16* Qp = Qr + (size_t)bh * 2048 * 64;
  const u16* Kp = Kr + (size_t)bh * 2048 * 64;
  const u16* Vp = Vt + (size_t)bh * 2048 * 64;
  __shared__ u16 P_all[2][32 * 64];  // per-wave private, XOR-swizzled
  __shared__ float Osh[64][33];      // wave1 O^T partial (d, q), +1 pad
  __shared__ float Msh[32][2];       // wave1 (m, l) per q-row
  u16* P_lds = P_all[wid];

  // Q fragments: aq[qg*2+ks]
  bf16x8 aq[4];
#pragma unroll
  for (int qg = 0; qg < 2; ++qg)
#pragma unroll
    for (int ks = 0; ks < 2; ++ks)
      aq[qg * 2 + ks] = *(const bf16x8*)&Qp[(size_t)(qbase + qg * 16 + cl) * 64 + ks * 32 + g * 8];

  f32x4 ot[8] = {};             // O^T frags: ot[qg*4+j], rows=d (j*16+g*4+r), col=q (qg*16+cl)
  float mrow[8], lrow[8];       // [qg*4+r], exp2 domain
#pragma unroll
  for (int r = 0; r < 8; ++r) { mrow[r] = -__builtin_inff(); lrow[r] = 0.f; }

  const int ktmax = qt >> 1;    // last (diagonal) K-tile index

  auto loadK = [&](bf16x8* dst, int kt_) {
#pragma unroll
    for (int n = 0; n < 4; ++n)
#pragma unroll
      for (int ks = 0; ks < 2; ++ks)
        dst[n * 2 + ks] = *(const bf16x8*)&Kp[(size_t)(kt_ * 64 + n * 16 + cl) * 64 + ks * 32 + g * 8];
  };
  auto loadV = [&](bf16x8* dst, int kt_) {
#pragma unroll
    for (int ks = 0; ks < 2; ++ks)
#pragma unroll
      for (int j = 0; j < 4; ++j)
        dst[ks * 4 + j] = *(const bf16x8*)&Vp[(size_t)(j * 16 + cl) * 2048 + kt_ * 64 + ks * 32 + g * 8];
  };

  auto tile = [&](const bf16x8* kf, const bf16x8* bv, int kt_, bool diag) {
    f32x4 s[8] = {};  // s[qg*4+n]: rows=q(g*4+r), col=k(n*16+cl)
#pragma unroll
    for (int qg = 0; qg < 2; ++qg)
#pragma unroll
      for (int n = 0; n < 4; ++n)
#pragma unroll
        for (int ks = 0; ks < 2; ++ks)
          s[qg * 4 + n] = __builtin_amdgcn_mfma_f32_16x16x32_bf16(aq[qg * 2 + ks], kf[n * 2 + ks],
                                                                  s[qg * 4 + n], 0, 0, 0);
    // scale (exp2 domain) + mask
    if (diag) {
#pragma unroll
      for (int qg = 0; qg < 2; ++qg)
#pragma unroll
        for (int n = 0; n < 4; ++n)
#pragma unroll
          for (int r = 0; r < 4; ++r) {
            int q = qbase + qg * 16 + g * 4 + r, k = kt_ * 64 + n * 16 + cl;
            s[qg * 4 + n][r] = (k <= q) ? s[qg * 4 + n][r] * SM_SCALE : -__builtin_inff();
          }
    } else {
#pragma unroll
      for (int i = 0; i < 8; ++i)
#pragma unroll
        for (int r = 0; r < 4; ++r) s[i][r] *= SM_SCALE;
    }
    bf16x8 ap[4];
#pragma unroll
    for (int qg = 0; qg < 2; ++qg) {
      float pmax[4], ef[4];
#pragma unroll
      for (int r = 0; r < 4; ++r) {
        float v = fmaxf(fmaxf(s[qg * 4 + 0][r], s[qg * 4 + 1][r]),
                        fmaxf(s[qg * 4 + 2][r], s[qg * 4 + 3][r]));
#pragma unroll
        for (int off = 1; off < 16; off <<= 1) v = fmaxf(v, __shfl_xor(v, off));
        pmax[r] = v;
      }
#pragma unroll
      for (int r = 0; r < 4; ++r) {
        float mnew = fmaxf(mrow[qg * 4 + r], pmax[r]);
        ef[r] = exp2f(mrow[qg * 4 + r] - mnew);
        mrow[qg * 4 + r] = mnew;
      }
      float rs[4] = {0.f, 0.f, 0.f, 0.f};
#pragma unroll
      for (int n = 0; n < 4; ++n)
#pragma unroll
        for (int r = 0; r < 4; ++r) {
          float p2 = exp2f(s[qg * 4 + n][r] - mrow[qg * 4 + r]);
          s[qg * 4 + n][r] = p2;
          rs[r] += p2;
          int row = qg * 16 + g * 4 + r;
          P_lds[(row * 64 + n * 16 + cl) ^ ((row & 7) << 3)] = f2bf(p2);
        }
#pragma unroll
      for (int r = 0; r < 4; ++r) {
        float v = rs[r];
#pragma unroll
        for (int off = 1; off < 16; off <<= 1) v += __shfl_xor(v, off);
        lrow[qg * 4 + r] = lrow[qg * 4 + r] * ef[r] + v;
      }
      // transpose ef to per-lane (for O^T col q=cl)
      int src = ((cl >> 2) << 4) | cl;
      float t0 = __shfl(ef[0], src), t1 = __shfl(ef[1], src);
      float t2 = __shfl(ef[2], src), t3 = __shfl(ef[3], src);
      float eft = (cl & 2) ? ((cl & 1) ? t3 : t2) : ((cl & 1) ? t1 : t0);
#pragma unroll
      for (int j = 0; j < 4; ++j)
#pragma unroll
        for (int r = 0; r < 4; ++r) ot[qg * 4 + j][r] *= eft;
      // read P fragments (B-role for swapped PV)
#pragma unroll
      for (int ks = 0; ks < 2; ++ks) {
        int rowr = qg * 16 + cl;
        ap[qg * 2 + ks] = *(const bf16x8*)&P_lds[(rowr * 64 + ks * 32 + g * 8) ^ ((rowr & 7) << 3)];
      }
    }
    // PV swapped: O^T = V^T * P^T
#pragma unroll
    for (int qg = 0; qg < 2; ++qg)
#pragma unroll
      for (int ks = 0; ks < 2; ++ks)
#pragma unroll
        for (int j = 0; j < 4; ++j)
          ot[qg * 4 + j] = __builtin_amdgcn_mfma_f32_16x16x32_bf16(bv[ks * 4 + j], ap[qg * 2 + ks],
                                                                   ot[qg * 4 + j], 0, 0, 0);
  };

  // split-K main loop: wave 'wid' owns kt = wid, wid+2, wid+4, ...
  bf16x8 kA[8], kB[8], bv[8];
  const int kts = wid;
  if (kts <= ktmax) {
    loadK(kA, kts);
    for (int kt = kts; kt <= ktmax; kt += 4) {
      loadV(bv, kt);
      if (kt + 2 <= ktmax) loadK(kB, kt + 2);
      tile(kA, bv, kt, kt == ktmax);
      if (kt + 2 <= ktmax) {
        loadV(bv, kt + 2);
        if (kt + 4 <= ktmax) loadK(kA, kt + 4);
        tile(kB, bv, kt + 2, kt + 2 == ktmax);
      }
    }
  }

  // ---- merge: wave1 deposits partials, wave0 combines + stores ----
  if (wid == 1) {
#pragma unroll
    for (int qg = 0; qg < 2; ++qg)
#pragma unroll
      for (int j = 0; j < 4; ++j)
#pragma unroll
        for (int r = 0; r < 4; ++r)
          Osh[j * 16 + g * 4 + r][qg * 16 + cl] = ot[qg * 4 + j][r];
    if (cl == 0) {
#pragma unroll
      for (int qg = 0; qg < 2; ++qg)
#pragma unroll
        for (int r = 0; r < 4; ++r) {
          Msh[qg * 16 + g * 4 + r][0] = mrow[qg * 4 + r];
          Msh[qg * 16 + g * 4 + r][1] = lrow[qg * 4 + r];
        }
    }
  }
  __syncthreads();
  if (wid == 0) {
#pragma unroll
    for (int qg = 0; qg < 2; ++qg) {
      // transpose own m,l to per-lane (col q = qg*16+cl)
      int src = ((cl >> 2) << 4) | cl;
      float m0 = __shfl(mrow[qg * 4 + 0], src), m1_ = __shfl(mrow[qg * 4 + 1], src);
      float m2 = __shfl(mrow[qg * 4 + 2], src), m3 = __shfl(mrow[qg * 4 + 3], src);
      float m0t = (cl & 2) ? ((cl & 1) ? m3 : m2) : ((cl & 1) ? m1_ : m0);
      float l0 = __shfl(lrow[qg * 4 + 0], src), l1_ = __shfl(lrow[qg * 4 + 1], src);
      float l2 = __shfl(lrow[qg * 4 + 2], src), l3 = __shfl(lrow[qg * 4 + 3], src);
      float l0t = (cl & 2) ? ((cl & 1) ? l3 : l2) : ((cl & 1) ? l1_ : l0);
      int q = qg * 16 + cl;
      float m1t = Msh[q][0], l1t = Msh[q][1];
      float mm = fmaxf(m0t, m1t);
      float a0 = exp2f(m0t - mm), a1 = exp2f(m1t - mm);
      float linv = 1.f / (l0t * a0 + l1t * a1);
      float s0 = a0 * linv, s1 = a1 * linv;
      int qglob = qbase + q;
#pragma unroll
      for (int j = 0; j < 4; ++j) {
        ushort4 v4;
        v4.x = f2bf(ot[qg * 4 + j][0] * s0 + Osh[j * 16 + g * 4 + 0][q] * s1);
        v4.y = f2bf(ot[qg * 4 + j][1] * s0 + Osh[j * 16 + g * 4 + 1][q] * s1);
        v4.z = f2bf(ot[qg * 4 + j][2] * s0 + Osh[j * 16 + g * 4 + 2][q] * s1);
        v4.w = f2bf(ot[qg * 4 + j][3] * s0 + Osh[j * 16 + g * 4 + 3][q] * s1);
        *(ushort4*)&hid[((size_t)(b * 2048) + qglob) * 1024 + h * 64 + j * 16 + g * 4] = v4;
      }
    }
  }
}

// ---------- output projection: out = hid @ Wo^T (f32 out) ----------

__launch_bounds__(256)
__global__ void out_gemm(const u16* __restrict__ hb, const u16* __restrict__ Wob,
                         float* __restrict__ out) {
  const int m0 = blockIdx.y * 128, n0 = blockIdx.x * 128;
  const int tid = threadIdx.x, w = tid >> 6, lane = tid & 63, g = lane >> 4, cl = lane & 15;
  const int wr = w >> 1, wc = w & 1;
  __shared__ u16 As[128][32], Bs[128][32];
  f32x4 acc[4][4] = {};
  for (int k0 = 0; k0 < 1024; k0 += 32) {
#pragma unroll
    for (int ch = 0; ch < 2; ++ch) {
      int t = tid + ch * 256;
      int row = t >> 2, col = (t & 3) * 8;
      async16(&hb[(size_t)(m0 + row) * 1024 + k0 + col], &As[row][col]);
      async16(&Wob[(size_t)(n0 + row) * 1024 + k0 + col], &Bs[row][col]);
    }
    __syncthreads();
    bf16x8 af[4], bfr[4];
#pragma unroll
    for (int i = 0; i < 4; ++i) af[i] = *(const bf16x8*)&As[wr * 64 + i * 16 + cl][g * 8];
#pragma unroll
    for (int j = 0; j < 4; ++j) bfr[j] = *(const bf16x8*)&Bs[wc * 64 + j * 16 + cl][g * 8];
#pragma unroll
    for (int i = 0; i < 4; ++i)
#pragma unroll
      for (int j = 0; j < 4; ++j)
        acc[i][j] = __builtin_amdgcn_mfma_f32_16x16x32_bf16(af[i], bfr[j], acc[i][j], 0, 0, 0);
    __syncthreads();
  }
#pragma unroll
  for (int i = 0; i < 4; ++i)
#pragma unroll
    for (int r = 0; r < 4; ++r) {
      int m = m0 + wr * 64 + i * 16 + g * 4 + r;
#pragma unroll
      for (int j = 0; j < 4; ++j)
        out[(size_t)m * 1024 + n0 + wc * 64 + j * 16 + cl] = acc[i][j][r];
    }
}

// ---------- launch ----------

extern "C" void kernel_launch(void* const* d_in, const int* in_sizes, int n_in,
                              void* d_out, int out_size, void* d_ws, size_t ws_size,
                              hipStream_t stream) {
  const float* x = (const float*)d_in[0];
  const float* Wq = (const float*)d_in[1];
  const float* Wk = (const float*)d_in[2];
  const float* Wv = (const float*)d_in[3];
  const float* Wo = (const float*)d_in[4];
  float* out = (float*)d_out;

  char* ws = (char*)d_ws;
  size_t off = 0;
  auto alloc = [&](size_t bytes) {
    void* p = ws + off;
    off += (bytes + 255) & ~(size_t)255;
    return p;
  };
  u16* xb = (u16*)alloc(4096ull * 1024 * 2);
  u16* Wqb = (u16*)alloc(1024ull * 1024 * 2);
  u16* Wkb = (u16*)alloc(1024ull * 1024 * 2);
  u16* Wvb = (u16*)alloc(1024ull * 1024 * 2);
  u16* Wob = (u16*)alloc(1024ull * 1024 * 2);
  u16* Qr = (u16*)alloc(4096ull * 1024 * 2);
  u16* Kr = (u16*)alloc(4096ull * 1024 * 2);
  u16* Vt = (u16*)alloc(4096ull * 1024 * 2);
  u16* hid = (u16*)alloc(4096ull * 1024 * 2);
  float* tcos = (float*)alloc(2048ull * 32 * 4);
  float* tsin = (float*)alloc(2048ull * 32 * 4);

  cast_bf16<<<1024, 256, 0, stream>>>((const float4*)x, (ushort4*)xb, 4096 * 1024 / 4);
  cast_w4<<<dim3(256, 4), 256, 0, stream>>>((const float4*)Wq, (const float4*)Wk,
                                            (const float4*)Wv, (const float4*)Wo,
                                            (ushort4*)Wqb, (ushort4*)Wkb,
                                            (ushort4*)Wvb, (ushort4*)Wob, 1024 * 1024 / 4);
  rope_table<<<256, 256, 0, stream>>>(tcos, tsin);

  qkv_gemm<<<dim3(8, 32, 3), 256, 0, stream>>>(xb, Wqb, Wkb, Wvb, tcos, tsin, Qr, Kr, Vt);
  attn_kernel<<<2048, 128, 0, stream>>>(Qr, Kr, Vt, hid);
  out_gemm<<<dim3(8, 32), 256, 0, stream>>>(hid, Wob, out);
}

// Round 8
// 243.927 us; speedup vs baseline: 1.1333x; 1.1171x over previous
//
#include <hip/hip_runtime.h>
#include <hip/hip_bf16.h>

typedef __attribute__((ext_vector_type(8))) short bf16x8;
typedef __attribute__((ext_vector_type(4))) float f32x4;
typedef unsigned short u16;
typedef unsigned int u32;

#define SM_SCALE 0.18033688f  // 0.125 * log2(e): softmax in exp2 domain

// ---------- helpers ----------

__device__ __forceinline__ u16 f2bf(float f) {
  __hip_bfloat16 h = __float2bfloat16(f);
  return *reinterpret_cast<u16*>(&h);
}

__device__ __forceinline__ void async16(const void* g, void* l) {
  __builtin_amdgcn_global_load_lds((const __attribute__((address_space(1))) u32*)g,
                                   (__attribute__((address_space(3))) u32*)l, 16, 0, 0);
}

// ---------- cast f32 -> bf16 (vectorized) ----------

__global__ void cast_bf16(const float4* __restrict__ src, ushort4* __restrict__ dst, int n4) {
  int stride = gridDim.x * blockDim.x;
  for (int i = blockIdx.x * blockDim.x + threadIdx.x; i < n4; i += stride) {
    float4 v = src[i];
    ushort4 o;
    o.x = f2bf(v.x); o.y = f2bf(v.y); o.z = f2bf(v.z); o.w = f2bf(v.w);
    dst[i] = o;
  }
}

__global__ void cast_w4(const float4* __restrict__ w0, const float4* __restrict__ w1,
                        const float4* __restrict__ w2, const float4* __restrict__ w3,
                        ushort4* __restrict__ o0, ushort4* __restrict__ o1,
                        ushort4* __restrict__ o2, ushort4* __restrict__ o3, int n4) {
  const float4* src = (blockIdx.y == 0) ? w0 : (blockIdx.y == 1) ? w1 : (blockIdx.y == 2) ? w2 : w3;
  ushort4* dst = (blockIdx.y == 0) ? o0 : (blockIdx.y == 1) ? o1 : (blockIdx.y == 2) ? o2 : o3;
  int stride = gridDim.x * blockDim.x;
  for (int i = blockIdx.x * blockDim.x + threadIdx.x; i < n4; i += stride) {
    float4 v = src[i];
    ushort4 o;
    o.x = f2bf(v.x); o.y = f2bf(v.y); o.z = f2bf(v.z); o.w = f2bf(v.w);
    dst[i] = o;
  }
}

// ---------- RoPE cos/sin table: [2048 pos][32 freq] ----------

__global__ void rope_table(float* __restrict__ tcos, float* __restrict__ tsin) {
  int idx = blockIdx.x * blockDim.x + threadIdx.x;
  if (idx >= 2048 * 32) return;
  int c = idx >> 5, j = idx & 31;
  float inv = powf(10000.f, -(float)j * (1.f / 32.f));
  float ang = (float)c * inv;
  tcos[idx] = cosf(ang);
  tsin[idx] = sinf(ang);
}

// ---------- QKV projection GEMM (y = x @ W^T), RoPE fused for Q/K ----------
// z=0: Q (+rope) -> [B,H,C,D], z=1: K (+rope) -> [B,H,C,D], z=2: V -> [B,H,D,C] (transposed)

__launch_bounds__(256)
__global__ void qkv_gemm(const u16* __restrict__ xb, const u16* __restrict__ Wqb,
                         const u16* __restrict__ Wkb, const u16* __restrict__ Wvb,
                         const float* __restrict__ tcos, const float* __restrict__ tsin,
                         u16* __restrict__ Qr, u16* __restrict__ Kr, u16* __restrict__ Vt) {
  const int z = blockIdx.z;
  const u16* W = (z == 0) ? Wqb : (z == 1) ? Wkb : Wvb;
  u16* dst = (z == 0) ? Qr : (z == 1) ? Kr : Vt;
  const int m0 = blockIdx.y * 128, n0 = blockIdx.x * 128;
  const int tid = threadIdx.x, w = tid >> 6, lane = tid & 63, g = lane >> 4, cl = lane & 15;
  const int wr = w >> 1, wc = w & 1;
  __shared__ u16 As[128][32], Bs[128][32];
  f32x4 acc[4][4] = {};
  for (int k0 = 0; k0 < 1024; k0 += 32) {
#pragma unroll
    for (int ch = 0; ch < 2; ++ch) {
      int t = tid + ch * 256;
      int row = t >> 2, col = (t & 3) * 8;
      async16(&xb[(size_t)(m0 + row) * 1024 + k0 + col], &As[row][col]);
      async16(&W[(size_t)(n0 + row) * 1024 + k0 + col], &Bs[row][col]);
    }
    __syncthreads();
    bf16x8 af[4], bfr[4];
#pragma unroll
    for (int i = 0; i < 4; ++i) af[i] = *(const bf16x8*)&As[wr * 64 + i * 16 + cl][g * 8];
#pragma unroll
    for (int j = 0; j < 4; ++j) bfr[j] = *(const bf16x8*)&Bs[wc * 64 + j * 16 + cl][g * 8];
#pragma unroll
    for (int i = 0; i < 4; ++i)
#pragma unroll
      for (int j = 0; j < 4; ++j)
        acc[i][j] = __builtin_amdgcn_mfma_f32_16x16x32_bf16(af[i], bfr[j], acc[i][j], 0, 0, 0);
    __syncthreads();
  }
  if (z < 2) {
#pragma unroll
    for (int i = 0; i < 4; ++i) {
      int mbase = m0 + wr * 64 + i * 16 + g * 4;
#pragma unroll
      for (int r = 0; r < 4; ++r) {
        int mm = mbase + r;
        int b = mm >> 11, pos = mm & 2047;
#pragma unroll
        for (int j = 0; j < 2; ++j) {
          int n = n0 + wc * 64 + j * 16 + cl;
          int h = n >> 6, dlo = n & 63;
          float a = acc[i][j][r], b2 = acc[i][j + 2][r];
          float cv = tcos[pos * 32 + dlo], sv = tsin[pos * 32 + dlo];
          float o1 = a * cv - b2 * sv;
          float o2 = b2 * cv + a * sv;
          size_t base = ((size_t)(b * 16 + h) * 2048 + pos) * 64;
          dst[base + dlo] = f2bf(o1);
          dst[base + dlo + 32] = f2bf(o2);
        }
      }
    }
  } else {
#pragma unroll
    for (int i = 0; i < 4; ++i) {
      int mbase = m0 + wr * 64 + i * 16 + g * 4;
      int b = mbase >> 11, pos = mbase & 2047;
#pragma unroll
      for (int j = 0; j < 4; ++j) {
        int n = n0 + wc * 64 + j * 16 + cl;
        int h = n >> 6, d = n & 63;
        ushort4 v4;
        v4.x = f2bf(acc[i][j][0]);
        v4.y = f2bf(acc[i][j][1]);
        v4.z = f2bf(acc[i][j][2]);
        v4.w = f2bf(acc[i][j][3]);
        *(ushort4*)&dst[((size_t)(b * 16 + h) * 64 + d) * 2048 + pos] = v4;
      }
    }
  }
}

// ---------- flash attention (causal), 1 wave/block, QBLK=32, swapped QK^T ----------
// S^T = mfma(K, Q): lane holds q-col (q=cl), kv spread over regs+g-groups.
// Softmax in-lane (15-op trees + 2 shfl_xor). P^T packed to LDS as B-frag for swapped PV.
// Grid 2048: xcd=bid&7, c=(bid>>3)&31, slot=bid>>8; qt = slot&1 ? c : 63-c
//  -> each CU gets 8 co-resident waves of 33+-1 K-tiles (exact causal balance).

__launch_bounds__(64)
__global__ void attn_kernel(const u16* __restrict__ Qr, const u16* __restrict__ Kr,
                            const u16* __restrict__ Vt, u16* __restrict__ hid) {
  const int bid = blockIdx.x;
  const int xcd = bid & 7, c = (bid >> 3) & 31, slot = bid >> 8;
  const int bh = xcd * 4 + (slot >> 1);
  const int qt = (slot & 1) ? c : 63 - c;
  const int lane = threadIdx.x, g = lane >> 4, cl = lane & 15;
  const int b = bh >> 4, h = bh & 15;
  const int qbase = qt * 32;
  const u16* Qp = Qr + (size_t)bh * 2048 * 64;
  const u16* Kp = Kr + (size_t)bh * 2048 * 64;
  const u16* Vp = Vt + (size_t)bh * 2048 * 64;
  __shared__ u16 Pt[32 * 64];  // P^T as [q][kv] u16, XOR-swizzled

  // Q fragments (B-operand for S^T): aq[qg*2+ks] = Q[q=qbase+qg*16+cl][d=ks*32+g*8+..]
  bf16x8 aq[4];
#pragma unroll
  for (int qg = 0; qg < 2; ++qg)
#pragma unroll
    for (int ks = 0; ks < 2; ++ks)
      aq[qg * 2 + ks] = *(const bf16x8*)&Qp[(size_t)(qbase + qg * 16 + cl) * 64 + ks * 32 + g * 8];

  f32x4 ot[8] = {};        // O^T frags: ot[qg*4+j], row d=j*16+g*4+r, col q=qg*16+cl
  float mrow[2], lrow[2];  // per-lane scalars (q=qg*16+cl), exp2 domain
  mrow[0] = mrow[1] = -__builtin_inff();
  lrow[0] = lrow[1] = 0.f;

  const int ktmax = qt >> 1;

  auto loadK = [&](bf16x8* dst, int kt_) {
#pragma unroll
    for (int n = 0; n < 4; ++n)
#pragma unroll
      for (int ks = 0; ks < 2; ++ks)
        dst[n * 2 + ks] = *(const bf16x8*)&Kp[(size_t)(kt_ * 64 + n * 16 + cl) * 64 + ks * 32 + g * 8];
  };
  auto loadV = [&](bf16x8* dst, int kt_) {
#pragma unroll
    for (int ks = 0; ks < 2; ++ks)
#pragma unroll
      for (int j = 0; j < 4; ++j)
        dst[ks * 4 + j] = *(const bf16x8*)&Vp[(size_t)(j * 16 + cl) * 2048 + kt_ * 64 + ks * 32 + g * 8];
  };

  auto tile = [&](const bf16x8* kf, const bf16x8* bv, int kt_, bool diag) {
    // S^T: st[qg*4+n] rows kv=n*16+g*4+r, col q=cl
    f32x4 st[8] = {};
#pragma unroll
    for (int qg = 0; qg < 2; ++qg)
#pragma unroll
      for (int n = 0; n < 4; ++n)
#pragma unroll
        for (int ks = 0; ks < 2; ++ks)
          st[qg * 4 + n] = __builtin_amdgcn_mfma_f32_16x16x32_bf16(kf[n * 2 + ks], aq[qg * 2 + ks],
                                                                   st[qg * 4 + n], 0, 0, 0);
    if (diag) {
#pragma unroll
      for (int qg = 0; qg < 2; ++qg) {
        int q = qbase + qg * 16 + cl;
#pragma unroll
        for (int n = 0; n < 4; ++n)
#pragma unroll
          for (int r = 0; r < 4; ++r) {
            int k = kt_ * 64 + n * 16 + g * 4 + r;
            st[qg * 4 + n][r] = (k <= q) ? st[qg * 4 + n][r] * SM_SCALE : -__builtin_inff();
          }
      }
    } else {
#pragma unroll
      for (int i = 0; i < 8; ++i)
#pragma unroll
        for (int r = 0; r < 4; ++r) st[i][r] *= SM_SCALE;
    }
    bf16x8 ap[4];
#pragma unroll
    for (int qg = 0; qg < 2; ++qg) {
      // in-lane max over 16 regs (tree), then combine 4 g-groups (2 shuffles)
      float v0 = fmaxf(fmaxf(st[qg * 4 + 0][0], st[qg * 4 + 0][1]),
                       fmaxf(st[qg * 4 + 0][2], st[qg * 4 + 0][3]));
      float v1 = fmaxf(fmaxf(st[qg * 4 + 1][0], st[qg * 4 + 1][1]),
                       fmaxf(st[qg * 4 + 1][2], st[qg * 4 + 1][3]));
      float v2 = fmaxf(fmaxf(st[qg * 4 + 2][0], st[qg * 4 + 2][1]),
                       fmaxf(st[qg * 4 + 2][2], st[qg * 4 + 2][3]));
      float v3 = fmaxf(fmaxf(st[qg * 4 + 3][0], st[qg * 4 + 3][1]),
                       fmaxf(st[qg * 4 + 3][2], st[qg * 4 + 3][3]));
      float v = fmaxf(fmaxf(v0, v1), fmaxf(v2, v3));
      v = fmaxf(v, __shfl_xor(v, 16));
      v = fmaxf(v, __shfl_xor(v, 32));
      float mnew = fmaxf(mrow[qg], v);
      float ef = exp2f(mrow[qg] - mnew);
      mrow[qg] = mnew;
      float rs = 0.f;
      int rowq = qg * 16 + cl;
#pragma unroll
      for (int n = 0; n < 4; ++n) {
        float p0 = exp2f(st[qg * 4 + n][0] - mnew);
        float p1 = exp2f(st[qg * 4 + n][1] - mnew);
        float p2 = exp2f(st[qg * 4 + n][2] - mnew);
        float p3 = exp2f(st[qg * 4 + n][3] - mnew);
        rs += (p0 + p1) + (p2 + p3);
        ushort4 v4;
        v4.x = f2bf(p0); v4.y = f2bf(p1); v4.z = f2bf(p2); v4.w = f2bf(p3);
        *(ushort4*)&Pt[(rowq * 64 + n * 16 + g * 4) ^ ((rowq & 7) << 3)] = v4;
      }
      rs += __shfl_xor(rs, 16);
      rs += __shfl_xor(rs, 32);
      lrow[qg] = lrow[qg] * ef + rs;
#pragma unroll
      for (int j = 0; j < 4; ++j)
#pragma unroll
        for (int r = 0; r < 4; ++r) ot[qg * 4 + j][r] *= ef;
      // P^T B-frags for PV: lane needs P[q=rowq][kv=ks*32+g*8+jj]
#pragma unroll
      for (int ks = 0; ks < 2; ++ks)
        ap[qg * 2 + ks] = *(const bf16x8*)&Pt[(rowq * 64 + ks * 32 + g * 8) ^ ((rowq & 7) << 3)];
    }
    // PV swapped: O^T = V^T * P^T
#pragma unroll
    for (int qg = 0; qg < 2; ++qg)
#pragma unroll
      for (int ks = 0; ks < 2; ++ks)
#pragma unroll
        for (int j = 0; j < 4; ++j)
          ot[qg * 4 + j] = __builtin_amdgcn_mfma_f32_16x16x32_bf16(bv[ks * 4 + j], ap[qg * 2 + ks],
                                                                   ot[qg * 4 + j], 0, 0, 0);
  };

  bf16x8 kA[8], kB[8], bv[8];
  loadK(kA, 0);
  for (int kt = 0; kt <= ktmax; kt += 2) {
    loadV(bv, kt);
    if (kt + 1 <= ktmax) loadK(kB, kt + 1);
    tile(kA, bv, kt, kt == ktmax);
    if (kt + 1 <= ktmax) {
      loadV(bv, kt + 1);
      if (kt + 2 <= ktmax) loadK(kA, kt + 2);
      tile(kB, bv, kt + 1, kt + 1 == ktmax);
    }
  }

  // epilogue: O^T row d=j*16+g*4+r, col q=qbase+qg*16+cl; l is per-lane scalar
#pragma unroll
  for (int qg = 0; qg < 2; ++qg) {
    float inv = 1.f / lrow[qg];
    int q = qbase + qg * 16 + cl;
#pragma unroll
    for (int j = 0; j < 4; ++j) {
      ushort4 v4;
      v4.x = f2bf(ot[qg * 4 + j][0] * inv);
      v4.y = f2bf(ot[qg * 4 + j][1] * inv);
      v4.z = f2bf(ot[qg * 4 + j][2] * inv);
      v4.w = f2bf(ot[qg * 4 + j][3] * inv);
      *(ushort4*)&hid[((size_t)(b * 2048) + q) * 1024 + h * 64 + j * 16 + g * 4] = v4;
    }
  }
}

// ---------- output projection: out = hid @ Wo^T (f32 out) ----------

__launch_bounds__(256)
__global__ void out_gemm(const u16* __restrict__ hb, const u16* __restrict__ Wob,
                         float* __restrict__ out) {
  const int m0 = blockIdx.y * 128, n0 = blockIdx.x * 128;
  const int tid = threadIdx.x, w = tid >> 6, lane = tid & 63, g = lane >> 4, cl = lane & 15;
  const int wr = w >> 1, wc = w & 1;
  __shared__ u16 As[128][32], Bs[128][32];
  f32x4 acc[4][4] = {};
  for (int k0 = 0; k0 < 1024; k0 += 32) {
#pragma unroll
    for (int ch = 0; ch < 2; ++ch) {
      int t = tid + ch * 256;
      int row = t >> 2, col = (t & 3) * 8;
      async16(&hb[(size_t)(m0 + row) * 1024 + k0 + col], &As[row][col]);
      async16(&Wob[(size_t)(n0 + row) * 1024 + k0 + col], &Bs[row][col]);
    }
    __syncthreads();
    bf16x8 af[4], bfr[4];
#pragma unroll
    for (int i = 0; i < 4; ++i) af[i] = *(const bf16x8*)&As[wr * 64 + i * 16 + cl][g * 8];
#pragma unroll
    for (int j = 0; j < 4; ++j) bfr[j] = *(const bf16x8*)&Bs[wc * 64 + j * 16 + cl][g * 8];
#pragma unroll
    for (int i = 0; i < 4; ++i)
#pragma unroll
      for (int j = 0; j < 4; ++j)
        acc[i][j] = __builtin_amdgcn_mfma_f32_16x16x32_bf16(af[i], bfr[j], acc[i][j], 0, 0, 0);
    __syncthreads();
  }
#pragma unroll
  for (int i = 0; i < 4; ++i)
#pragma unroll
    for (int r = 0; r < 4; ++r) {
      int m = m0 + wr * 64 + i * 16 + g * 4 + r;
#pragma unroll
      for (int j = 0; j < 4; ++j)
        out[(size_t)m * 1024 + n0 + wc * 64 + j * 16 + cl] = acc[i][j][r];
    }
}

// ---------- launch ----------

extern "C" void kernel_launch(void* const* d_in, const int* in_sizes, int n_in,
                              void* d_out, int out_size, void* d_ws, size_t ws_size,
                              hipStream_t stream) {
  const float* x = (const float*)d_in[0];
  const float* Wq = (const float*)d_in[1];
  const float* Wk = (const float*)d_in[2];
  const float* Wv = (const float*)d_in[3];
  const float* Wo = (const float*)d_in[4];
  float* out = (float*)d_out;

  char* ws = (char*)d_ws;
  size_t off = 0;
  auto alloc = [&](size_t bytes) {
    void* p = ws + off;
    off += (bytes + 255) & ~(size_t)255;
    return p;
  };
  u16* xb = (u16*)alloc(4096ull * 1024 * 2);
  u16* Wqb = (u16*)alloc(1024ull * 1024 * 2);
  u16* Wkb = (u16*)alloc(1024ull * 1024 * 2);
  u16* Wvb = (u16*)alloc(1024ull * 1024 * 2);
  u16* Wob = (u16*)alloc(1024ull * 1024 * 2);
  u16* Qr = (u16*)alloc(4096ull * 1024 * 2);
  u16* Kr = (u16*)alloc(4096ull * 1024 * 2);
  u16* Vt = (u16*)alloc(4096ull * 1024 * 2);
  u16* hid = (u16*)alloc(4096ull * 1024 * 2);
  float* tcos = (float*)alloc(2048ull * 32 * 4);
  float* tsin = (float*)alloc(2048ull * 32 * 4);

  cast_bf16<<<1024, 256, 0, stream>>>((const float4*)x, (ushort4*)xb, 4096 * 1024 / 4);
  cast_w4<<<dim3(256, 4), 256, 0, stream>>>((const float4*)Wq, (const float4*)Wk,
                                            (const float4*)Wv, (const float4*)Wo,
                                            (ushort4*)Wqb, (ushort4*)Wkb,
                                            (ushort4*)Wvb, (ushort4*)Wob, 1024 * 1024 / 4);
  rope_table<<<256, 256, 0, stream>>>(tcos, tsin);

  qkv_gemm<<<dim3(8, 32, 3), 256, 0, stream>>>(xb, Wqb, Wkb, Wvb, tcos, tsin, Qr, Kr, Vt);
  attn_kernel<<<2048, 64, 0, stream>>>(Qr, Kr, Vt, hid);
  out_gemm<<<dim3(8, 32), 256, 0, stream>>>(hid, Wob, out);
}